// Round 5
// baseline (469.051 us; speedup 1.0000x reference)
//
#include <hip/hip_runtime.h>
#include <hip/hip_bf16.h>
#include <math.h>

typedef __bf16 bf16;
typedef __bf16 bf16x8 __attribute__((ext_vector_type(8)));
typedef __bf16 bf16x4 __attribute__((ext_vector_type(4)));
typedef float  f32x4  __attribute__((ext_vector_type(4)));
typedef short  sv4    __attribute__((ext_vector_type(4)));

#define B_  2
#define T_  2048
#define DM  2048
#define H_  32
#define DH  64

__device__ __forceinline__ bf16x8 load8(const bf16* p) {
    return *reinterpret_cast<const bf16x8*>(p);
}

__device__ __forceinline__ void gld16(const bf16* g, bf16* l) {
    __builtin_amdgcn_global_load_lds(
        (const __attribute__((address_space(1))) unsigned int*)g,
        (__attribute__((address_space(3))) unsigned int*)l, 16, 0, 0);
}

// ---------------- convert fp32 -> bf16 ----------------
__global__ void k_convert(const float* __restrict__ in, bf16* __restrict__ out, int n4) {
    int i = blockIdx.x * blockDim.x + threadIdx.x;
    if (i < n4) {
        float4 v = reinterpret_cast<const float4*>(in)[i];
        bf16x4 o;
        o[0] = (bf16)v.x; o[1] = (bf16)v.y; o[2] = (bf16)v.z; o[3] = (bf16)v.w;
        reinterpret_cast<bf16x4*>(out)[i] = o;
    }
}

// ---------------- transpose + convert weights ----------------
__global__ void k_transposeW(const float* __restrict__ Wq, const float* __restrict__ Wk,
                             const float* __restrict__ Wv, const float* __restrict__ Wo,
                             bf16* __restrict__ WqT, bf16* __restrict__ WkT,
                             bf16* __restrict__ WvT, bf16* __restrict__ WoT) {
    const float* in; bf16* out;
    switch (blockIdx.z) {
        case 0: in = Wq; out = WqT; break;
        case 1: in = Wk; out = WkT; break;
        case 2: in = Wv; out = WvT; break;
        default: in = Wo; out = WoT; break;
    }
    __shared__ float tile[32][33];
    int tx = threadIdx.x, ty = threadIdx.y;
    int x0 = blockIdx.x * 32, y0 = blockIdx.y * 32;
    #pragma unroll
    for (int i = 0; i < 4; i++)
        tile[ty + i*8][tx] = in[(size_t)(y0 + ty + i*8) * DM + x0 + tx];
    __syncthreads();
    #pragma unroll
    for (int i = 0; i < 4; i++)
        out[(size_t)(x0 + ty + i*8) * DM + y0 + tx] = (bf16)tile[tx][ty + i*8];
}

// ---------------- m97-style GEMM + XOR-swizzled LDS + optional fused RoPE ----
// C[M,*] = A[M,2048] @ BT[N,2048]^T. block 256 = 4 waves (2x2), tile 128x128.
// LDS rows 32 bf16 (64B) unpadded (global_load_lds); 16B segs XOR-swizzled by
// (row>>1)&3 so the b128 fragment reads are 2-way (free) instead of 8-way.
template<int OUT_BF16, int ROPE>
__global__ __launch_bounds__(256)
void k_gemm(const bf16* __restrict__ A, const bf16* __restrict__ BT,
            void* __restrict__ Cout, int ldc) {
    constexpr int K = 2048;
    __shared__ bf16 ldsA[128 * 32];
    __shared__ bf16 ldsB[128 * 32];
    int tid = threadIdx.x;
    int lane = tid & 63, w = tid >> 6;
    int l16 = lane & 15, quad = lane >> 4;
    int wm = w >> 1, wn = w & 1;
    int mblk = blockIdx.y * 128, nblk = blockIdx.x * 128;

    f32x4 acc[4][4] = {};

    int sgz = ((lane & 3) ^ ((lane >> 3) & 3)) * 8;      // swizzled global seg
    const bf16* gA = A  + (size_t)(mblk + w * 32 + (lane >> 2)) * K + sgz;
    const bf16* gB = BT + (size_t)(nblk + w * 32 + (lane >> 2)) * K + sgz;
    bf16* lA = ldsA + w * 1024;
    bf16* lB = ldsB + w * 1024;
    int sA = (quad ^ ((l16 >> 1) & 3)) * 8;              // swizzled read seg

    for (int k0 = 0; k0 < K; k0 += 32) {
        gld16(gA + k0,          lA);
        gld16(gA + 16 * K + k0, lA + 512);
        gld16(gB + k0,          lB);
        gld16(gB + 16 * K + k0, lB + 512);
        __syncthreads();
        bf16x8 af[4], bfr[4];
        #pragma unroll
        for (int s = 0; s < 4; s++)
            af[s] = *reinterpret_cast<bf16x8*>(&ldsA[(wm * 64 + s * 16 + l16) * 32 + sA]);
        #pragma unroll
        for (int t = 0; t < 4; t++)
            bfr[t] = *reinterpret_cast<bf16x8*>(&ldsB[(wn * 64 + t * 16 + l16) * 32 + sA]);
        #pragma unroll
        for (int s = 0; s < 4; s++)
            #pragma unroll
            for (int t = 0; t < 4; t++)
                acc[s][t] = __builtin_amdgcn_mfma_f32_16x16x32_bf16(af[s], bfr[t], acc[s][t], 0, 0, 0);
        __syncthreads();
    }

    // fused RoPE: each wave's 64 cols = one head; pair acc[s][t] with acc[s][t+2]
    if (ROPE && nblk < 4096) {
        #pragma unroll
        for (int t = 0; t < 2; t++) {
            int dim = t * 16 + l16;                      // 0..31
            float invf = __builtin_amdgcn_exp2f(-(float)dim * 0.41524101186092037f);
            #pragma unroll
            for (int s = 0; s < 4; s++) {
                #pragma unroll
                for (int r = 0; r < 4; r++) {
                    int row = mblk + wm * 64 + s * 16 + quad * 4 + r;
                    float ang = (float)(row & 2047) * invf;
                    float sn, cs;
                    __sincosf(ang, &sn, &cs);
                    float x1 = acc[s][t][r], x2 = acc[s][t + 2][r];
                    acc[s][t][r]     = x1 * cs - x2 * sn;
                    acc[s][t + 2][r] = x2 * cs + x1 * sn;
                }
            }
        }
    }

    #pragma unroll
    for (int s = 0; s < 4; s++) {
        int row = mblk + wm * 64 + s * 16 + quad * 4;
        #pragma unroll
        for (int t = 0; t < 4; t++) {
            int col = nblk + wn * 64 + t * 16 + l16;
            #pragma unroll
            for (int r = 0; r < 4; r++) {
                if (OUT_BF16)
                    reinterpret_cast<bf16*>(Cout)[(size_t)(row + r) * ldc + col] = (bf16)acc[s][t][r];
                else
                    reinterpret_cast<float*>(Cout)[(size_t)(row + r) * ldc + col] = acc[s][t][r];
            }
        }
    }
}

// ---------------- v = l1*v1 + l2*v_gemm -> vT [B,H,DH,T] bf16 ----------------
__global__ void k_combinev(const float* __restrict__ v1, const bf16* __restrict__ qkv,
                           const float* __restrict__ l1p, const float* __restrict__ l2p,
                           bf16* __restrict__ vT) {
    __shared__ float tile[64 * 33];
    float l1 = l1p[0], l2 = l2p[0];
    int b = blockIdx.y >> 5, h = blockIdx.y & 31;
    int t0 = blockIdx.x * 32;
    int tid = threadIdx.x;
    int d = tid & 63, tr = tid >> 6;
    #pragma unroll
    for (int i = 0; i < 8; i++) {
        int t = t0 + i * 4 + tr;
        size_t iv1 = ((size_t)(b * T_ + t)) * 2048 + h * 64 + d;
        size_t ivg = ((size_t)(b * T_ + t)) * 6144 + 4096 + h * 64 + d;
        tile[d * 33 + i * 4 + tr] = l1 * v1[iv1] + l2 * (float)qkv[ivg];
    }
    __syncthreads();
    int tl = tid & 31, dr = tid >> 5;
    #pragma unroll
    for (int j = 0; j < 8; j++) {
        int d2 = dr + j * 8;
        vT[((size_t)((b * H_ + h) * 64 + d2)) * T_ + t0 + tl] = (bf16)tile[d2 * 33 + tl];
    }
}

// ---------------- causal flash attention, S^T form ----------------
// grid (16, 64) = 1024 blocks (4/CU). Block = 4 waves, 64 queries (16/wave).
// Pass pairing (qt, 31-qt) -> uniform 33 key-tiles of 64 keys.
// K/V staged via global_load_lds into unpadded 64-elem rows with 16B-seg XOR
// swizzle (key row&7) -> 2-way-free b128/b64 fragment reads.
__global__ __launch_bounds__(256)
void k_attn(const bf16* __restrict__ qkv, const bf16* __restrict__ vT, bf16* __restrict__ o) {
    __shared__ bf16 ldsK[64 * 64];   // [key][dh], swizzled
    __shared__ bf16 ldsV[64 * 64];   // [dh][key], swizzled
    int bx = blockIdx.x;             // 0..15
    int bh = blockIdx.y;
    int b = bh >> 5, h = bh & 31;
    int tid = threadIdx.x;
    int lane = tid & 63, w = tid >> 6;
    int l16 = lane & 15, quad = lane >> 4;

    // staging: wave w owns rows w*16..w*16+15 (2 gld16 calls of 8 rows each)
    int rl = lane >> 3, sg = ((lane & 7) ^ rl) * 8;
    const bf16* kgl = qkv + ((size_t)(b * T_) + w * 16 + rl) * 6144 + 2048 + h * 64 + sg;
    const bf16* vgl = vT + ((size_t)bh * DH + w * 16 + rl) * T_ + sg;
    bf16* lKw = ldsK + w * 16 * 64;
    bf16* lVw = ldsV + w * 16 * 64;

    int skey = (quad ^ (l16 & 7)) * 8;            // K read seg, dh 0..31
    int skey2 = ((quad + 4) ^ (l16 & 7)) * 8;     // K read seg, dh 32..63

    #pragma unroll 1
    for (int pass = 0; pass < 2; pass++) {
        int qt = pass ? (31 - bx) : bx;
        int qbase = qt * 64 + w * 16;

        // Q fragments, prescaled by 1/8 * log2(e)
        size_t qrow = (size_t)(b * T_ + qbase + l16) * 6144 + h * 64;
        bf16x8 qf[2];
        #pragma unroll
        for (int half = 0; half < 2; half++) {
            bf16x8 v = load8(qkv + qrow + half * 32 + quad * 8);
            #pragma unroll
            for (int e = 0; e < 8; e++) v[e] = (bf16)((float)v[e] * 0.1803368801f);
            qf[half] = v;
        }

        f32x4 accO[4] = {};
        float m_ = -1e30f, pl = 0.f;

        int nkt = qt + 1;
        for (int kt = 0; kt < nkt; kt++) {
            int key0 = kt * 64;
            #pragma unroll
            for (int j = 0; j < 2; j++) {
                gld16(kgl + (size_t)(key0 + j * 8) * 6144, lKw + j * 512);
                gld16(vgl + (size_t)(j * 8) * T_ + key0,   lVw + j * 512);
            }
            __syncthreads();

            bool diag = (kt == qt);                  // wave-uniform
            // active ks subtiles: key0+ks*16 <= qbase+15
            // non-diag tiles: all 4 active, no masking
            f32x4 st[4];
            sv4 pk[4];
            #pragma unroll
            for (int ks = 0; ks < 4; ks++) {
                if (!diag || key0 + ks * 16 <= qbase + 15) {
                    bf16x8 kf0 = *reinterpret_cast<bf16x8*>(&ldsK[(ks * 16 + l16) * 64 + skey]);
                    bf16x8 kf1 = *reinterpret_cast<bf16x8*>(&ldsK[(ks * 16 + l16) * 64 + skey2]);
                    f32x4 z = {};
                    z = __builtin_amdgcn_mfma_f32_16x16x32_bf16(kf0, qf[0], z, 0, 0, 0);
                    z = __builtin_amdgcn_mfma_f32_16x16x32_bf16(kf1, qf[1], z, 0, 0, 0);
                    st[ks] = z;
                } else {
                    st[ks] = (f32x4){-3e38f, -3e38f, -3e38f, -3e38f};
                }
            }

            if (diag) {                              // mask only on diagonal tile
                int qcol = qbase + l16;
                #pragma unroll
                for (int ks = 0; ks < 4; ks++)
                    #pragma unroll
                    for (int r = 0; r < 4; r++)
                        if (key0 + ks * 16 + quad * 4 + r > qcol) st[ks][r] = -3e38f;
            }

            float mx = st[0][0];
            #pragma unroll
            for (int ks = 0; ks < 4; ks++)
                #pragma unroll
                for (int r = 0; r < 4; r++) mx = fmaxf(mx, st[ks][r]);
            mx = fmaxf(mx, __shfl_xor(mx, 16));
            mx = fmaxf(mx, __shfl_xor(mx, 32));
            if (__any(mx > m_)) {
                float nm = fmaxf(m_, mx);
                float alpha = __builtin_amdgcn_exp2f(m_ - nm);
                m_ = nm;
                pl *= alpha;
                #pragma unroll
                for (int n2 = 0; n2 < 4; n2++) accO[n2] *= alpha;
            }
            float rsum = 0.f;
            #pragma unroll
            for (int ks = 0; ks < 4; ks++) {
                bf16x4 ph;
                #pragma unroll
                for (int r = 0; r < 4; r++) {
                    float p = __builtin_amdgcn_exp2f(st[ks][r] - m_);
                    rsum += p;
                    ph[r] = (bf16)p;
                }
                pk[ks] = __builtin_bit_cast(sv4, ph);
            }
            pl += rsum;

            // O^T += V^T @ P^T (16x16x16); skip fully-masked diag subtiles
            #pragma unroll
            for (int ks = 0; ks < 4; ks++) {
                if (!diag || key0 + ks * 16 <= qbase + 15) {
                    int svf = ((ks * 2 + (quad >> 1)) ^ (l16 & 7)) * 8 + (quad & 1) * 4;
                    #pragma unroll
                    for (int n2 = 0; n2 < 4; n2++) {
                        sv4 vf = *reinterpret_cast<sv4*>(&ldsV[(n2 * 16 + l16) * 64 + svf]);
                        accO[n2] = __builtin_amdgcn_mfma_f32_16x16x16bf16_1k(
                            vf, pk[ks], accO[n2], 0, 0, 0);
                    }
                }
            }
            __syncthreads();
        }

        // epilogue
        float l = pl;
        l += __shfl_xor(l, 16);
        l += __shfl_xor(l, 32);
        float inv = 1.0f / l;
        int query = qbase + l16;
        #pragma unroll
        for (int n2 = 0; n2 < 4; n2++) {
            bf16x4 ov;
            #pragma unroll
            for (int r = 0; r < 4; r++) ov[r] = (bf16)(accO[n2][r] * inv);
            *reinterpret_cast<bf16x4*>(
                &o[(size_t)(b * T_ + query) * DM + h * 64 + n2 * 16 + quad * 4]) = ov;
        }
    }
}

extern "C" void kernel_launch(void* const* d_in, const int* in_sizes, int n_in,
                              void* d_out, int out_size, void* d_ws, size_t ws_size,
                              hipStream_t stream) {
    const float* hs   = (const float*)d_in[0];
    const float* v1   = (const float*)d_in[1];
    const float* lam1 = (const float*)d_in[2];
    const float* Wq   = (const float*)d_in[3];
    const float* Wk   = (const float*)d_in[4];
    const float* Wv   = (const float*)d_in[5];
    const float* Wo   = (const float*)d_in[6];
    const float* lam2 = (const float*)d_in[7];

    char* ws = (char*)d_ws;
    bf16* hs_bf = (bf16*)(ws);                            // 16 MiB
    bf16* Wcat  = (bf16*)(ws + 16777216);                 // WqT|WkT|WvT, 24 MiB
    bf16* WoT   = (bf16*)(ws + 41943040);                 // 8 MiB
    bf16* qkv   = (bf16*)(ws + 50331648);                 // 4096x6144 bf16 = 48 MiB
    bf16* vT_bf = (bf16*)(ws + 100663296);                // 16 MiB
    bf16* o_bf  = (bf16*)(ws + 117440512);                // 16 MiB -> 128 MiB

    k_convert<<<8192, 256, 0, stream>>>(hs, hs_bf, 2097152);
    k_transposeW<<<dim3(64, 64, 4), dim3(32, 8), 0, stream>>>(
        Wq, Wk, Wv, Wo, Wcat, Wcat + 4194304, Wcat + 8388608, WoT);

    k_gemm<1, 1><<<dim3(48, 32), 256, 0, stream>>>(hs_bf, Wcat, (void*)qkv, 6144);

    k_combinev<<<dim3(64, 64), 256, 0, stream>>>(v1, qkv, lam1, lam2, vT_bf);

    k_attn<<<dim3(16, 64), 256, 0, stream>>>(qkv, vT_bf, o_bf);

    k_gemm<0, 0><<<dim3(16, 32), 256, 0, stream>>>(o_bf, WoT, d_out, 2048);
}

// Round 6
// 442.033 us; speedup vs baseline: 1.0611x; 1.0611x over previous
//
#include <hip/hip_runtime.h>
#include <hip/hip_bf16.h>
#include <math.h>

typedef __bf16 bf16;
typedef __bf16 bf16x8 __attribute__((ext_vector_type(8)));
typedef __bf16 bf16x4 __attribute__((ext_vector_type(4)));
typedef float  f32x4  __attribute__((ext_vector_type(4)));
typedef short  sv4    __attribute__((ext_vector_type(4)));

#define B_  2
#define T_  2048
#define DM  2048
#define H_  32
#define DH  64

__device__ __forceinline__ bf16x8 load8(const bf16* p) {
    return *reinterpret_cast<const bf16x8*>(p);
}

__device__ __forceinline__ void gld16(const bf16* g, bf16* l) {
    __builtin_amdgcn_global_load_lds(
        (const __attribute__((address_space(1))) unsigned int*)g,
        (__attribute__((address_space(3))) unsigned int*)l, 16, 0, 0);
}

// ---------------- convert fp32 -> bf16 ----------------
__global__ void k_convert(const float* __restrict__ in, bf16* __restrict__ out, int n4) {
    int i = blockIdx.x * blockDim.x + threadIdx.x;
    if (i < n4) {
        float4 v = reinterpret_cast<const float4*>(in)[i];
        bf16x4 o;
        o[0] = (bf16)v.x; o[1] = (bf16)v.y; o[2] = (bf16)v.z; o[3] = (bf16)v.w;
        reinterpret_cast<bf16x4*>(out)[i] = o;
    }
}

// ---------------- transpose + convert weights ----------------
__global__ void k_transposeW(const float* __restrict__ Wq, const float* __restrict__ Wk,
                             const float* __restrict__ Wv, const float* __restrict__ Wo,
                             bf16* __restrict__ WqT, bf16* __restrict__ WkT,
                             bf16* __restrict__ WvT, bf16* __restrict__ WoT) {
    const float* in; bf16* out;
    switch (blockIdx.z) {
        case 0: in = Wq; out = WqT; break;
        case 1: in = Wk; out = WkT; break;
        case 2: in = Wv; out = WvT; break;
        default: in = Wo; out = WoT; break;
    }
    __shared__ float tile[32][33];
    int tx = threadIdx.x, ty = threadIdx.y;
    int x0 = blockIdx.x * 32, y0 = blockIdx.y * 32;
    #pragma unroll
    for (int i = 0; i < 4; i++)
        tile[ty + i*8][tx] = in[(size_t)(y0 + ty + i*8) * DM + x0 + tx];
    __syncthreads();
    #pragma unroll
    for (int i = 0; i < 4; i++)
        out[(size_t)(x0 + ty + i*8) * DM + y0 + tx] = (bf16)tile[tx][ty + i*8];
}

// ---------------- m97-style GEMM, XOR-swizzled LDS (conflict-free) -----------
// C[M,*] = A[M,2048] @ BT[N,2048]^T. block 256 = 4 waves (2x2), tile 128x128.
// LDS rows 32 bf16 (64B) unpadded (global_load_lds); 16B segs XOR-swizzled by
// (row>>1)&3 -> b128 fragment reads are 2-way (free) instead of 8-way.
// NOTE: no fused epilogue work here — keeping VGPR ~76 for 7 waves/SIMD
// (round-5 fused RoPE pushed VGPR to 100, occupancy 31->21%, +37us. Reverted.)
template<int OUT_BF16>
__global__ __launch_bounds__(256)
void k_gemm(const bf16* __restrict__ A, const bf16* __restrict__ BT,
            void* __restrict__ Cout, int ldc) {
    constexpr int K = 2048;
    __shared__ bf16 ldsA[128 * 32];
    __shared__ bf16 ldsB[128 * 32];
    int tid = threadIdx.x;
    int lane = tid & 63, w = tid >> 6;
    int l16 = lane & 15, quad = lane >> 4;
    int wm = w >> 1, wn = w & 1;
    int mblk = blockIdx.y * 128, nblk = blockIdx.x * 128;

    f32x4 acc[4][4] = {};

    int sgz = ((lane & 3) ^ ((lane >> 3) & 3)) * 8;      // swizzled global seg
    const bf16* gA = A  + (size_t)(mblk + w * 32 + (lane >> 2)) * K + sgz;
    const bf16* gB = BT + (size_t)(nblk + w * 32 + (lane >> 2)) * K + sgz;
    bf16* lA = ldsA + w * 1024;
    bf16* lB = ldsB + w * 1024;
    int sA = (quad ^ ((l16 >> 1) & 3)) * 8;              // swizzled read seg

    for (int k0 = 0; k0 < K; k0 += 32) {
        gld16(gA + k0,          lA);
        gld16(gA + 16 * K + k0, lA + 512);
        gld16(gB + k0,          lB);
        gld16(gB + 16 * K + k0, lB + 512);
        __syncthreads();
        bf16x8 af[4], bfr[4];
        #pragma unroll
        for (int s = 0; s < 4; s++)
            af[s] = *reinterpret_cast<bf16x8*>(&ldsA[(wm * 64 + s * 16 + l16) * 32 + sA]);
        #pragma unroll
        for (int t = 0; t < 4; t++)
            bfr[t] = *reinterpret_cast<bf16x8*>(&ldsB[(wn * 64 + t * 16 + l16) * 32 + sA]);
        #pragma unroll
        for (int s = 0; s < 4; s++)
            #pragma unroll
            for (int t = 0; t < 4; t++)
                acc[s][t] = __builtin_amdgcn_mfma_f32_16x16x32_bf16(af[s], bfr[t], acc[s][t], 0, 0, 0);
        __syncthreads();
    }

    #pragma unroll
    for (int s = 0; s < 4; s++) {
        int row = mblk + wm * 64 + s * 16 + quad * 4;
        #pragma unroll
        for (int t = 0; t < 4; t++) {
            int col = nblk + wn * 64 + t * 16 + l16;
            #pragma unroll
            for (int r = 0; r < 4; r++) {
                if (OUT_BF16)
                    reinterpret_cast<bf16*>(Cout)[(size_t)(row + r) * ldc + col] = (bf16)acc[s][t][r];
                else
                    reinterpret_cast<float*>(Cout)[(size_t)(row + r) * ldc + col] = acc[s][t][r];
            }
        }
    }
}

// ---------------- RoPE cos/sin table: tab[t*32+i] = (cos, sin)(t * 10000^(-i/32))
__global__ void k_tab(float2* __restrict__ tab) {
    int id = blockIdx.x * 256 + threadIdx.x;   // 65536
    int i = id & 31, t = id >> 5;
    float inv = __builtin_amdgcn_exp2f(-(float)i * 0.41524101186092037f);
    float ang = (float)t * inv;
    float s, c;
    __sincosf(ang, &s, &c);
    tab[id] = make_float2(c, s);
}

// ---------------- RoPE apply, vectorized, table-based ------------------------
// thread owns dims [8j..8j+8) x pair-partner [+32..) of one (b,t,sel,h) row.
__global__ void k_rope(bf16* __restrict__ qkv, const float2* __restrict__ tab) {
    int id = blockIdx.x * 256 + threadIdx.x;   // 2^20 threads
    int j   = id & 3;
    int h   = (id >> 2) & 31;
    int sel = (id >> 7) & 1;
    int t   = (id >> 8) & 2047;
    int b   = id >> 19;
    size_t base = ((size_t)(b * T_ + t)) * 6144 + sel * 2048 + h * 64 + j * 8;
    bf16x8 x1 = load8(qkv + base);
    bf16x8 x2 = load8(qkv + base + 32);
    const float2* tp = tab + t * 32 + j * 8;
    bf16x8 o1, o2;
    #pragma unroll
    for (int e = 0; e < 8; e++) {
        float c = tp[e].x, s = tp[e].y;
        float a = (float)x1[e], v = (float)x2[e];
        o1[e] = (bf16)(a * c - v * s);
        o2[e] = (bf16)(v * c + a * s);
    }
    *reinterpret_cast<bf16x8*>(qkv + base)      = o1;
    *reinterpret_cast<bf16x8*>(qkv + base + 32) = o2;
}

// ---------------- v = l1*v1 + l2*v_gemm -> vT [B,H,DH,T] bf16 ----------------
__global__ void k_combinev(const float* __restrict__ v1, const bf16* __restrict__ qkv,
                           const float* __restrict__ l1p, const float* __restrict__ l2p,
                           bf16* __restrict__ vT) {
    __shared__ float tile[64 * 33];
    float l1 = l1p[0], l2 = l2p[0];
    int b = blockIdx.y >> 5, h = blockIdx.y & 31;
    int t0 = blockIdx.x * 32;
    int tid = threadIdx.x;
    int d = tid & 63, tr = tid >> 6;
    #pragma unroll
    for (int i = 0; i < 8; i++) {
        int t = t0 + i * 4 + tr;
        size_t iv1 = ((size_t)(b * T_ + t)) * 2048 + h * 64 + d;
        size_t ivg = ((size_t)(b * T_ + t)) * 6144 + 4096 + h * 64 + d;
        tile[d * 33 + i * 4 + tr] = l1 * v1[iv1] + l2 * (float)qkv[ivg];
    }
    __syncthreads();
    int tl = tid & 31, dr = tid >> 5;
    #pragma unroll
    for (int j = 0; j < 8; j++) {
        int d2 = dr + j * 8;
        vT[((size_t)((b * H_ + h) * 64 + d2)) * T_ + t0 + tl] = (bf16)tile[d2 * 33 + tl];
    }
}

// ---------------- causal flash attention, S^T form ----------------
// grid (16, 64) = 1024 blocks. Block = 4 waves, 64 queries (16/wave).
// Pass pairing (qt, 31-qt) -> uniform 33 key-tiles of 64 keys.
__global__ __launch_bounds__(256)
void k_attn(const bf16* __restrict__ qkv, const bf16* __restrict__ vT, bf16* __restrict__ o) {
    __shared__ bf16 ldsK[64 * 64];   // [key][dh], swizzled
    __shared__ bf16 ldsV[64 * 64];   // [dh][key], swizzled
    int bx = blockIdx.x;             // 0..15
    int bh = blockIdx.y;
    int b = bh >> 5, h = bh & 31;
    int tid = threadIdx.x;
    int lane = tid & 63, w = tid >> 6;
    int l16 = lane & 15, quad = lane >> 4;

    int rl = lane >> 3, sg = ((lane & 7) ^ rl) * 8;
    const bf16* kgl = qkv + ((size_t)(b * T_) + w * 16 + rl) * 6144 + 2048 + h * 64 + sg;
    const bf16* vgl = vT + ((size_t)bh * DH + w * 16 + rl) * T_ + sg;
    bf16* lKw = ldsK + w * 16 * 64;
    bf16* lVw = ldsV + w * 16 * 64;

    int skey = (quad ^ (l16 & 7)) * 8;            // K read seg, dh 0..31
    int skey2 = ((quad + 4) ^ (l16 & 7)) * 8;     // K read seg, dh 32..63

    #pragma unroll 1
    for (int pass = 0; pass < 2; pass++) {
        int qt = pass ? (31 - bx) : bx;
        int qbase = qt * 64 + w * 16;

        size_t qrow = (size_t)(b * T_ + qbase + l16) * 6144 + h * 64;
        bf16x8 qf[2];
        #pragma unroll
        for (int half = 0; half < 2; half++) {
            bf16x8 v = load8(qkv + qrow + half * 32 + quad * 8);
            #pragma unroll
            for (int e = 0; e < 8; e++) v[e] = (bf16)((float)v[e] * 0.1803368801f);
            qf[half] = v;
        }

        f32x4 accO[4] = {};
        float m_ = -1e30f, pl = 0.f;

        int nkt = qt + 1;
        for (int kt = 0; kt < nkt; kt++) {
            int key0 = kt * 64;
            #pragma unroll
            for (int j = 0; j < 2; j++) {
                gld16(kgl + (size_t)(key0 + j * 8) * 6144, lKw + j * 512);
                gld16(vgl + (size_t)(j * 8) * T_ + key0,   lVw + j * 512);
            }
            __syncthreads();

            bool diag = (kt == qt);
            f32x4 st[4];
            sv4 pk[4];
            #pragma unroll
            for (int ks = 0; ks < 4; ks++) {
                if (!diag || key0 + ks * 16 <= qbase + 15) {
                    bf16x8 kf0 = *reinterpret_cast<bf16x8*>(&ldsK[(ks * 16 + l16) * 64 + skey]);
                    bf16x8 kf1 = *reinterpret_cast<bf16x8*>(&ldsK[(ks * 16 + l16) * 64 + skey2]);
                    f32x4 z = {};
                    z = __builtin_amdgcn_mfma_f32_16x16x32_bf16(kf0, qf[0], z, 0, 0, 0);
                    z = __builtin_amdgcn_mfma_f32_16x16x32_bf16(kf1, qf[1], z, 0, 0, 0);
                    st[ks] = z;
                } else {
                    st[ks] = (f32x4){-3e38f, -3e38f, -3e38f, -3e38f};
                }
            }

            if (diag) {
                int qcol = qbase + l16;
                #pragma unroll
                for (int ks = 0; ks < 4; ks++)
                    #pragma unroll
                    for (int r = 0; r < 4; r++)
                        if (key0 + ks * 16 + quad * 4 + r > qcol) st[ks][r] = -3e38f;
            }

            float mx = st[0][0];
            #pragma unroll
            for (int ks = 0; ks < 4; ks++)
                #pragma unroll
                for (int r = 0; r < 4; r++) mx = fmaxf(mx, st[ks][r]);
            mx = fmaxf(mx, __shfl_xor(mx, 16));
            mx = fmaxf(mx, __shfl_xor(mx, 32));
            if (__any(mx > m_)) {
                float nm = fmaxf(m_, mx);
                float alpha = __builtin_amdgcn_exp2f(m_ - nm);
                m_ = nm;
                pl *= alpha;
                #pragma unroll
                for (int n2 = 0; n2 < 4; n2++) accO[n2] *= alpha;
            }
            float rsum = 0.f;
            #pragma unroll
            for (int ks = 0; ks < 4; ks++) {
                bf16x4 ph;
                #pragma unroll
                for (int r = 0; r < 4; r++) {
                    float p = __builtin_amdgcn_exp2f(st[ks][r] - m_);
                    rsum += p;
                    ph[r] = (bf16)p;
                }
                pk[ks] = __builtin_bit_cast(sv4, ph);
            }
            pl += rsum;

            #pragma unroll
            for (int ks = 0; ks < 4; ks++) {
                if (!diag || key0 + ks * 16 <= qbase + 15) {
                    int svf = ((ks * 2 + (quad >> 1)) ^ (l16 & 7)) * 8 + (quad & 1) * 4;
                    #pragma unroll
                    for (int n2 = 0; n2 < 4; n2++) {
                        sv4 vf = *reinterpret_cast<sv4*>(&ldsV[(n2 * 16 + l16) * 64 + svf]);
                        accO[n2] = __builtin_amdgcn_mfma_f32_16x16x16bf16_1k(
                            vf, pk[ks], accO[n2], 0, 0, 0);
                    }
                }
            }
            __syncthreads();
        }

        float l = pl;
        l += __shfl_xor(l, 16);
        l += __shfl_xor(l, 32);
        float inv = 1.0f / l;
        int query = qbase + l16;
        #pragma unroll
        for (int n2 = 0; n2 < 4; n2++) {
            bf16x4 ov;
            #pragma unroll
            for (int r = 0; r < 4; r++) ov[r] = (bf16)(accO[n2][r] * inv);
            *reinterpret_cast<bf16x4*>(
                &o[(size_t)(b * T_ + query) * DM + h * 64 + n2 * 16 + quad * 4]) = ov;
        }
    }
}

extern "C" void kernel_launch(void* const* d_in, const int* in_sizes, int n_in,
                              void* d_out, int out_size, void* d_ws, size_t ws_size,
                              hipStream_t stream) {
    const float* hs   = (const float*)d_in[0];
    const float* v1   = (const float*)d_in[1];
    const float* lam1 = (const float*)d_in[2];
    const float* Wq   = (const float*)d_in[3];
    const float* Wk   = (const float*)d_in[4];
    const float* Wv   = (const float*)d_in[5];
    const float* Wo   = (const float*)d_in[6];
    const float* lam2 = (const float*)d_in[7];

    char* ws = (char*)d_ws;
    bf16* hs_bf = (bf16*)(ws);                            // 16 MiB (dead after QKV gemm)
    float2* tab = (float2*)(ws);                          // 512 KB, reuses hs_bf region
    bf16* Wcat  = (bf16*)(ws + 16777216);                 // WqT|WkT|WvT, 24 MiB
    bf16* WoT   = (bf16*)(ws + 41943040);                 // 8 MiB
    bf16* qkv   = (bf16*)(ws + 50331648);                 // 4096x6144 bf16 = 48 MiB
    bf16* vT_bf = (bf16*)(ws + 100663296);                // 16 MiB
    bf16* o_bf  = (bf16*)(ws + 117440512);                // 16 MiB -> 128 MiB

    k_convert<<<8192, 256, 0, stream>>>(hs, hs_bf, 2097152);
    k_transposeW<<<dim3(64, 64, 4), dim3(32, 8), 0, stream>>>(
        Wq, Wk, Wv, Wo, Wcat, Wcat + 4194304, Wcat + 8388608, WoT);

    k_gemm<1><<<dim3(48, 32), 256, 0, stream>>>(hs_bf, Wcat, (void*)qkv, 6144);

    k_tab<<<256, 256, 0, stream>>>(tab);                  // hs_bf dead from here
    k_rope<<<4096, 256, 0, stream>>>(qkv, tab);

    k_combinev<<<dim3(64, 64), 256, 0, stream>>>(v1, qkv, lam1, lam2, vT_bf);

    k_attn<<<dim3(16, 64), 256, 0, stream>>>(qkv, vT_bf, o_bf);

    k_gemm<0><<<dim3(16, 32), 256, 0, stream>>>(o_bf, WoT, d_out, 2048);
}